// Round 1
// baseline (334.994 us; speedup 1.0000x reference)
//
#include <hip/hip_runtime.h>

typedef __bf16 bf16;
typedef bf16 bf16x8 __attribute__((ext_vector_type(8)));
typedef float f32x4 __attribute__((ext_vector_type(4)));

#define TPB 256
#define CHP 72   // padded LDS row stride in ushorts for a 64-element K-chunk (144B = 9*16B)

__device__ inline unsigned short f2bf(float f){
  union{ bf16 h; unsigned short u; } v; v.h = (bf16)f; return v.u;
}
__device__ inline float bf2f(unsigned short u){
  union{ unsigned short u; bf16 h; } v; v.u = u; return (float)v.h;
}
__device__ inline unsigned int pk2(float a, float b){
  return (unsigned int)f2bf(a) | ((unsigned int)f2bf(b) << 16);
}

struct __align__(16) SharedBlk {
  unsigned short xlds[128*CHP];   // 18432 B
  unsigned short wlds[128*CHP];   // 18432 B
  float red[128*2*2];             // [row][wavecol][sum,sq]
  float stats[128*2];             // [row][mean,rstd]
};

// ---- staging helpers (one 64-wide K chunk, 128 rows) ----
__device__ inline void stage_w(const unsigned short* __restrict__ Wt, int KTOT, int k0,
                               unsigned short* wlds, int tid){
#pragma unroll
  for (int p = tid; p < 128*16; p += TPB){
    int n = p >> 4, q = p & 15;
    *(uint2*)(wlds + n*CHP + q*4) = *(const uint2*)(Wt + (size_t)n*KTOT + k0 + q*4);
  }
}
__device__ inline void stage_x_f32(const float* __restrict__ src, unsigned short* xlds, int tid){
#pragma unroll
  for (int p = tid; p < 128*32; p += TPB){
    int r = p >> 5, kp = p & 31;
    float2 v = *(const float2*)(src + (size_t)r*128 + kp*2);
    *(unsigned int*)(xlds + r*CHP + kp*2) = pk2(v.x, v.y);
  }
}
__device__ inline void stage_x_bf16(const unsigned short* __restrict__ src, unsigned short* xlds, int tid){
#pragma unroll
  for (int p = tid; p < 128*16; p += TPB){
    int r = p >> 4, q = p & 15;
    *(uint2*)(xlds + r*CHP + q*4) = *(const uint2*)(src + (size_t)r*128 + q*4);
  }
}
__device__ inline void stage_x_gather(const float* __restrict__ coarse_b, const int* __restrict__ idx_b,
                                      int n0, int k0, unsigned short* xlds, int tid){
#pragma unroll
  for (int p = tid; p < 128*32; p += TPB){
    int r = p >> 5, kp = p & 31;
    int ci = idx_b[n0 + r];
    float2 v;
    if ((unsigned)ci < 512u) v = *(const float2*)(coarse_b + (size_t)ci*128 + k0 + kp*2);
    else { v.x = 0.f; v.y = 0.f; }
    *(unsigned int*)(xlds + r*CHP + kp*2) = pk2(v.x, v.y);
  }
}
__device__ inline void stage_x_bcast(const float* __restrict__ gm_b, float scale, int k0,
                                     unsigned short* xlds, int tid){
#pragma unroll
  for (int p = tid; p < 128*32; p += TPB){
    int r = p >> 5, kp = p & 31;
    float a = gm_b[k0 + kp*2] * scale;
    float b = gm_b[k0 + kp*2 + 1] * scale;
    *(unsigned int*)(xlds + r*CHP + kp*2) = pk2(a, b);
  }
}

// ---- 64-K-chunk MFMA accumulate: block tile 128x128, wave tile 64x64 (2x2 waves) ----
__device__ inline void gemm_chunk(const unsigned short* xlds, const unsigned short* wlds,
                                  f32x4 acc[4][4], int wr, int wc, int il, int lg){
#pragma unroll
  for (int kk = 0; kk < 2; ++kk){
    bf16x8 a[4], b[4];
#pragma unroll
    for (int t = 0; t < 4; ++t)
      a[t] = *(const bf16x8*)(xlds + (wr*64 + t*16 + il)*CHP + kk*32 + lg*8);
#pragma unroll
    for (int t = 0; t < 4; ++t)
      b[t] = *(const bf16x8*)(wlds + (wc*64 + t*16 + il)*CHP + kk*32 + lg*8);
#pragma unroll
    for (int rt = 0; rt < 4; ++rt)
#pragma unroll
      for (int ct = 0; ct < 4; ++ct)
        acc[rt][ct] = __builtin_amdgcn_mfma_f32_16x16x32_bf16(a[rt], b[ct], acc[rt][ct], 0, 0, 0);
  }
}

// ---- LN stats from acc (+bias), into sh.stats ----
__device__ inline void ln_stats(SharedBlk& sh, f32x4 acc[4][4], const float bia[4],
                                int wr, int wc, int il, int lg, int tid){
#pragma unroll
  for (int rt = 0; rt < 4; ++rt)
#pragma unroll
    for (int ri = 0; ri < 4; ++ri){
      float s = 0.f, q = 0.f;
#pragma unroll
      for (int ct = 0; ct < 4; ++ct){
        float z = acc[rt][ct][ri] + bia[ct];
        s += z; q += z*z;
      }
#pragma unroll
      for (int m = 1; m < 16; m <<= 1){ s += __shfl_xor(s, m); q += __shfl_xor(q, m); }
      if (il == 0){
        int row = wr*64 + rt*16 + lg*4 + ri;
        sh.red[(row*2 + wc)*2 + 0] = s;
        sh.red[(row*2 + wc)*2 + 1] = q;
      }
    }
  __syncthreads();
  if (tid < 128){
    float s = sh.red[(tid*2+0)*2+0] + sh.red[(tid*2+1)*2+0];
    float q = sh.red[(tid*2+0)*2+1] + sh.red[(tid*2+1)*2+1];
    float mean = s * (1.f/128.f);
    float var  = q * (1.f/128.f) - mean*mean;
    sh.stats[tid*2+0] = mean;
    sh.stats[tid*2+1] = rsqrtf(var + 1e-5f);
  }
  __syncthreads();
}

// =======================  kernels  =======================

// pooled segment-mean: one block per (b,c); scan idx, gather+sum matching fine rows
__global__ __launch_bounds__(TPB) void k_pool(const float* __restrict__ fine,
                                              const int* __restrict__ idx,
                                              unsigned short* __restrict__ pooled){
  int b = blockIdx.x >> 9, c = blockIdx.x & 511;
  __shared__ int list[4096];
  __shared__ int cnt;
  __shared__ float part[128];
  int tid = threadIdx.x;
  if (tid == 0) cnt = 0;
  __syncthreads();
  const int* idx_b = idx + b*4096;
  for (int i = tid; i < 4096; i += TPB)
    if (idx_b[i] == c){ int p = atomicAdd(&cnt, 1); list[p] = i; }
  __syncthreads();
  int n = cnt;
  int h = tid & 127, half = tid >> 7;
  float s = 0.f;
  const float* fb = fine + (size_t)b*4096*128;
  for (int m = half; m < n; m += 2) s += fb[(size_t)list[m]*128 + h];
  if (half) part[h] = s;
  __syncthreads();
  if (!half){
    float mean = (s + part[h]) / fmaxf((float)n, 1.f);
    pooled[((size_t)(b*512 + c))*128 + h] = f2bf(mean);
  }
}

// per-batch sum over N of global_features (scaled at use time)
__global__ __launch_bounds__(TPB) void k_gmean(const float* __restrict__ glob,
                                               float* __restrict__ gmean){
  int b = blockIdx.x >> 5, s = blockIdx.x & 31;
  int tid = threadIdx.x;
  int h = tid & 127, half = tid >> 7;
  __shared__ float part[128];
  const float* gb = glob + ((size_t)b*4096 + s*128)*128;
  float acc = 0.f;
  for (int r = half; r < 128; r += 2) acc += gb[(size_t)r*128 + h];
  if (half) part[h] = acc;
  __syncthreads();
  if (!half) atomicAdd(&gmean[b*128 + h], acc + part[h]);
}

// W [K][128] fp32 -> Wt [128][K] bf16
__global__ void k_prep(const float* __restrict__ Wp, const float* __restrict__ Wu,
                       const float* __restrict__ Wg, const float* __restrict__ Wgl,
                       unsigned short* __restrict__ WtP, unsigned short* __restrict__ WtU,
                       unsigned short* __restrict__ WtG, unsigned short* __restrict__ WtGl){
  int i = blockIdx.x * blockDim.x + threadIdx.x;
  if (i < 16384){
    int n = i >> 7, k = i & 127;
    WtP[n*128 + k] = f2bf(Wp[k*128 + n]);
    WtU[n*128 + k] = f2bf(Wu[k*128 + n]);
  }
  if (i < 32768){
    int n = i >> 8, k = i & 255;
    WtG [n*256 + k] = f2bf(Wg [k*128 + n]);
    WtGl[n*256 + k] = f2bf(Wgl[k*128 + n]);
  }
}

// y = relu(LN(x@W + b)*g + be) -> bf16 out.  XMODE 0: x = gather(coarse, idx); 1: x = bf16 buffer
template<int XMODE>
__global__ __launch_bounds__(TPB) void k_block_ln(const float* __restrict__ xf,
                                                  const unsigned short* __restrict__ xb,
                                                  const int* __restrict__ idx,
                                                  const unsigned short* __restrict__ Wt,
                                                  const float* __restrict__ bias,
                                                  const float* __restrict__ gam,
                                                  const float* __restrict__ bet,
                                                  unsigned short* __restrict__ out,
                                                  int nlog){
  __shared__ SharedBlk sh;
  int tid = threadIdx.x;
  int row0 = blockIdx.x * 128;
  int b = row0 >> nlog;
  int r0 = row0 - (b << nlog);
  int wave = tid >> 6, lane = tid & 63;
  int wr = wave >> 1, wc = wave & 1, il = lane & 15, lg = lane >> 4;

  f32x4 acc[4][4] = {};
#pragma unroll
  for (int c = 0; c < 2; ++c){
    int k0 = c*64;
    stage_w(Wt, 128, k0, sh.wlds, tid);
    if (XMODE == 0) stage_x_gather(xf + (size_t)b*512*128, idx + b*4096, r0, k0, sh.xlds, tid);
    else            stage_x_bf16(xb + (size_t)row0*128 + k0, sh.xlds, tid);
    __syncthreads();
    gemm_chunk(sh.xlds, sh.wlds, acc, wr, wc, il, lg);
    __syncthreads();
  }
  float bia[4], gm[4], bt[4];
#pragma unroll
  for (int ct = 0; ct < 4; ++ct){
    int col = wc*64 + ct*16 + il;
    bia[ct] = bias[col]; gm[ct] = gam[col]; bt[ct] = bet[col];
  }
  ln_stats(sh, acc, bia, wr, wc, il, lg, tid);
#pragma unroll
  for (int rt = 0; rt < 4; ++rt)
#pragma unroll
    for (int ri = 0; ri < 4; ++ri){
      int row = wr*64 + rt*16 + lg*4 + ri;
      float mean = sh.stats[row*2+0], rstd = sh.stats[row*2+1];
      size_t gro = (size_t)(row0 + row) * 128;
#pragma unroll
      for (int ct = 0; ct < 4; ++ct){
        int col = wc*64 + ct*16 + il;
        float z = acc[rt][ct][ri] + bia[ct];
        float y = (z - mean) * rstd * gm[ct] + bt[ct];
        out[gro + col] = f2bf(fmaxf(y, 0.f));
      }
    }
}

// gate = sigmoid([a,u]@Wg + b); out = gate*a + (1-gate)*u   (fp32 out)
__global__ __launch_bounds__(TPB) void k_gate(const float* __restrict__ a_src,
                                              const unsigned short* __restrict__ u_src,
                                              const unsigned short* __restrict__ Wt,
                                              const float* __restrict__ bias,
                                              float* __restrict__ out){
  __shared__ SharedBlk sh;
  int tid = threadIdx.x;
  int row0 = blockIdx.x * 128;
  int wave = tid >> 6, lane = tid & 63;
  int wr = wave >> 1, wc = wave & 1, il = lane & 15, lg = lane >> 4;

  f32x4 acc[4][4] = {};
#pragma unroll
  for (int c = 0; c < 4; ++c){
    int k0 = c*64;
    stage_w(Wt, 256, k0, sh.wlds, tid);
    if (k0 < 128) stage_x_f32 (a_src + (size_t)row0*128 + k0,        sh.xlds, tid);
    else          stage_x_bf16(u_src + (size_t)row0*128 + (k0-128), sh.xlds, tid);
    __syncthreads();
    gemm_chunk(sh.xlds, sh.wlds, acc, wr, wc, il, lg);
    __syncthreads();
  }
  float bia[4];
#pragma unroll
  for (int ct = 0; ct < 4; ++ct) bia[ct] = bias[wc*64 + ct*16 + il];
#pragma unroll
  for (int rt = 0; rt < 4; ++rt)
#pragma unroll
    for (int ri = 0; ri < 4; ++ri){
      int row = wr*64 + rt*16 + lg*4 + ri;
      size_t gro = (size_t)(row0 + row) * 128;
#pragma unroll
      for (int ct = 0; ct < 4; ++ct){
        int col = wc*64 + ct*16 + il;
        float z = acc[rt][ct][ri] + bia[ct];
        float g = 1.f / (1.f + __expf(-z));
        float f = a_src[gro + col];
        float u = bf2f(u_src[gro + col]);
        out[gro + col] = g*f + (1.f - g)*u;
      }
    }
}

// wg = relu(LN([v,g]@Wgl + b)*gam + bet); out = v + 0.1*wg  (in place on v)
// GMODE 0: g per-row fp32 buffer; GMODE 1: broadcast gmean[b]*gscale
template<int GMODE>
__global__ __launch_bounds__(TPB) void k_glob(const float* __restrict__ v_src,
                                              const float* __restrict__ g_src,
                                              float gscale,
                                              const unsigned short* __restrict__ Wt,
                                              const float* __restrict__ bias,
                                              const float* __restrict__ gam,
                                              const float* __restrict__ bet,
                                              float* __restrict__ out,
                                              int nlog){
  __shared__ SharedBlk sh;
  int tid = threadIdx.x;
  int row0 = blockIdx.x * 128;
  int b = row0 >> nlog;
  int wave = tid >> 6, lane = tid & 63;
  int wr = wave >> 1, wc = wave & 1, il = lane & 15, lg = lane >> 4;

  f32x4 acc[4][4] = {};
#pragma unroll
  for (int c = 0; c < 4; ++c){
    int k0 = c*64;
    stage_w(Wt, 256, k0, sh.wlds, tid);
    if (k0 < 128)           stage_x_f32  (v_src + (size_t)row0*128 + k0,        sh.xlds, tid);
    else if (GMODE == 0)    stage_x_f32  (g_src + (size_t)row0*128 + (k0-128), sh.xlds, tid);
    else                    stage_x_bcast(g_src + (size_t)b*128, gscale, k0-128, sh.xlds, tid);
    __syncthreads();
    gemm_chunk(sh.xlds, sh.wlds, acc, wr, wc, il, lg);
    __syncthreads();
  }
  float bia[4], gm[4], bt[4];
#pragma unroll
  for (int ct = 0; ct < 4; ++ct){
    int col = wc*64 + ct*16 + il;
    bia[ct] = bias[col]; gm[ct] = gam[col]; bt[ct] = bet[col];
  }
  ln_stats(sh, acc, bia, wr, wc, il, lg, tid);
#pragma unroll
  for (int rt = 0; rt < 4; ++rt)
#pragma unroll
    for (int ri = 0; ri < 4; ++ri){
      int row = wr*64 + rt*16 + lg*4 + ri;
      float mean = sh.stats[row*2+0], rstd = sh.stats[row*2+1];
      size_t gro = (size_t)(row0 + row) * 128;
#pragma unroll
      for (int ct = 0; ct < 4; ++ct){
        int col = wc*64 + ct*16 + il;
        float z = acc[rt][ct][ri] + bia[ct];
        float y = fmaxf((z - mean) * rstd * gm[ct] + bt[ct], 0.f);
        out[gro + col] = v_src[gro + col] + 0.1f * y;
      }
    }
}

extern "C" void kernel_launch(void* const* d_in, const int* in_sizes, int n_in,
                              void* d_out, int out_size, void* d_ws, size_t ws_size,
                              hipStream_t stream){
  const float* fine    = (const float*)d_in[0];
  const float* coarse  = (const float*)d_in[1];
  const float* glob    = (const float*)d_in[2];
  const int*   idx     = (const int*)  d_in[3];
  const float* W_pool  = (const float*)d_in[4];
  const float* b_pool  = (const float*)d_in[5];
  const float* g_pool  = (const float*)d_in[6];
  const float* be_pool = (const float*)d_in[7];
  const float* W_unpool  = (const float*)d_in[8];
  const float* b_unpool  = (const float*)d_in[9];
  const float* g_unpool  = (const float*)d_in[10];
  const float* be_unpool = (const float*)d_in[11];
  const float* W_gate = (const float*)d_in[12];
  const float* b_gate = (const float*)d_in[13];
  const float* W_glob = (const float*)d_in[14];
  const float* b_glob = (const float*)d_in[15];
  const float* g_glob = (const float*)d_in[16];
  const float* be_glob= (const float*)d_in[17];

  const int B = 32, N = 4096, C = 512;
  float* out_fine   = (float*)d_out;
  float* out_coarse = out_fine + (size_t)B*N*128;

  char* w = (char*)d_ws;
  unsigned short* WtP  = (unsigned short*)w; w += 128*128*2;
  unsigned short* WtU  = (unsigned short*)w; w += 128*128*2;
  unsigned short* WtG  = (unsigned short*)w; w += 128*256*2;
  unsigned short* WtGl = (unsigned short*)w; w += 128*256*2;
  float* gmean = (float*)w;                  w += B*128*4;
  unsigned short* pooled = (unsigned short*)w; w += (size_t)B*C*128*2;
  unsigned short* cf     = (unsigned short*)w; w += (size_t)B*C*128*2;
  unsigned short* ufine  = (unsigned short*)w; w += (size_t)B*N*128*2;

  hipMemsetAsync(gmean, 0, B*128*4, stream);
  k_prep<<<128, TPB, 0, stream>>>(W_pool, W_unpool, W_gate, W_glob, WtP, WtU, WtG, WtGl);
  k_pool<<<B*C, TPB, 0, stream>>>(fine, idx, pooled);
  k_gmean<<<B*32, TPB, 0, stream>>>(glob, gmean);

  // fine_from_coarse = block(gather) ; coarse_from_fine = block(pooled)
  k_block_ln<0><<<(B*N)/128, TPB, 0, stream>>>(coarse, nullptr, idx, WtU,
                                               b_unpool, g_unpool, be_unpool, ufine, 12);
  k_block_ln<1><<<(B*C)/128, TPB, 0, stream>>>(nullptr, pooled, nullptr, WtP,
                                               b_pool, g_pool, be_pool, cf, 9);
  // gated fusion
  k_gate<<<(B*N)/128, TPB, 0, stream>>>(fine,   ufine, WtG, b_gate, out_fine);
  k_gate<<<(B*C)/128, TPB, 0, stream>>>(coarse, cf,    WtG, b_gate, out_coarse);
  // global injection
  k_glob<0><<<(B*N)/128, TPB, 0, stream>>>(out_fine,   glob,  1.0f,        WtGl,
                                           b_glob, g_glob, be_glob, out_fine, 12);
  k_glob<1><<<(B*C)/128, TPB, 0, stream>>>(out_coarse, gmean, 1.f/4096.f,  WtGl,
                                           b_glob, g_glob, be_glob, out_coarse, 9);
}

// Round 3
// 261.417 us; speedup vs baseline: 1.2815x; 1.2815x over previous
//
#include <hip/hip_runtime.h>

typedef __bf16 bf16;
typedef bf16 bf16x8 __attribute__((ext_vector_type(8)));
typedef float f32x4 __attribute__((ext_vector_type(4)));

#define TPB 256
#define CHP 72   // padded LDS row stride (ushorts) for a 64-wide K chunk: 144B = 9*16B

__device__ inline unsigned short f2bf(float f){
  union{ bf16 h; unsigned short u; } v; v.h = (bf16)f; return v.u;
}
__device__ inline float bf2f(unsigned short u){
  union{ unsigned short u; bf16 h; } v; v.u = u; return (float)v.h;
}
__device__ inline unsigned int pk2(float a, float b){
  return (unsigned int)f2bf(a) | ((unsigned int)f2bf(b) << 16);
}

struct __align__(16) MegaShared {
  unsigned short xlds[128*CHP];      // 18432 B
  unsigned short wlds[128*CHP];      // 18432 B
  unsigned short ubuf[2][128*CHP];   // 36864 B  (u intermediate, 2 x 64-K chunks)
  float red[128*2*2];                // 2048 B
  float stats[128*2];                // 1024 B
};                                   // total 76800 B -> 2 blocks/CU

// ---- staging helpers (one 64-wide K chunk, 128 rows) ----
__device__ inline void stage_w(const unsigned short* __restrict__ Wt, int KTOT, int k0,
                               unsigned short* wlds, int tid){
#pragma unroll
  for (int p = tid; p < 128*16; p += TPB){
    int n = p >> 4, q = p & 15;
    *(uint2*)(wlds + n*CHP + q*4) = *(const uint2*)(Wt + (size_t)n*KTOT + k0 + q*4);
  }
}
__device__ inline void stage_x_f32(const float* __restrict__ src, unsigned short* xlds, int tid){
#pragma unroll
  for (int p = tid; p < 128*16; p += TPB){
    int r = p >> 4, q = p & 15;
    float4 v = *(const float4*)(src + (size_t)r*128 + q*4);
    uint2 o; o.x = pk2(v.x, v.y); o.y = pk2(v.z, v.w);
    *(uint2*)(xlds + r*CHP + q*4) = o;
  }
}
__device__ inline void stage_x_bf16(const unsigned short* __restrict__ src, unsigned short* xlds, int tid){
#pragma unroll
  for (int p = tid; p < 128*16; p += TPB){
    int r = p >> 4, q = p & 15;
    *(uint2*)(xlds + r*CHP + q*4) = *(const uint2*)(src + (size_t)r*128 + q*4);
  }
}
__device__ inline void stage_x_gather(const float* __restrict__ coarse_b, const int* __restrict__ idx_b,
                                      int n0, int k0, unsigned short* xlds, int tid){
#pragma unroll
  for (int p = tid; p < 128*16; p += TPB){
    int r = p >> 4, q = p & 15;
    int ci = idx_b[n0 + r];
    float4 v;
    if ((unsigned)ci < 512u) v = *(const float4*)(coarse_b + (size_t)ci*128 + k0 + q*4);
    else { v.x = v.y = v.z = v.w = 0.f; }
    uint2 o; o.x = pk2(v.x, v.y); o.y = pk2(v.z, v.w);
    *(uint2*)(xlds + r*CHP + q*4) = o;
  }
}
__device__ inline void stage_x_bcast(const float* __restrict__ gm_b, float scale, int k0,
                                     unsigned short* xlds, int tid){
#pragma unroll
  for (int p = tid; p < 128*16; p += TPB){
    int r = p >> 4, q = p & 15;
    float4 v = *(const float4*)(gm_b + k0 + q*4);
    uint2 o; o.x = pk2(v.x*scale, v.y*scale); o.y = pk2(v.z*scale, v.w*scale);
    *(uint2*)(xlds + r*CHP + q*4) = o;
  }
}

// ---- 64-K-chunk MFMA accumulate: block tile 128x128, wave tile 64x64 (2x2 waves) ----
__device__ inline void gemm_chunk(const unsigned short* xsrc, const unsigned short* wsrc,
                                  f32x4 acc[4][4], int wr, int wc, int il, int lg){
#pragma unroll
  for (int kk = 0; kk < 2; ++kk){
    bf16x8 a[4], b[4];
#pragma unroll
    for (int t = 0; t < 4; ++t)
      a[t] = *(const bf16x8*)(xsrc + (wr*64 + t*16 + il)*CHP + kk*32 + lg*8);
#pragma unroll
    for (int t = 0; t < 4; ++t)
      b[t] = *(const bf16x8*)(wsrc + (wc*64 + t*16 + il)*CHP + kk*32 + lg*8);
#pragma unroll
    for (int rt = 0; rt < 4; ++rt)
#pragma unroll
      for (int ct = 0; ct < 4; ++ct)
        acc[rt][ct] = __builtin_amdgcn_mfma_f32_16x16x32_bf16(a[rt], b[ct], acc[rt][ct], 0, 0, 0);
  }
}

// ---- LN stats from acc (+bias), into sh.stats ----
__device__ inline void ln_stats(MegaShared& sh, f32x4 acc[4][4], const float bia[4],
                                int wr, int wc, int il, int lg, int tid){
#pragma unroll
  for (int rt = 0; rt < 4; ++rt)
#pragma unroll
    for (int ri = 0; ri < 4; ++ri){
      float s = 0.f, q = 0.f;
#pragma unroll
      for (int ct = 0; ct < 4; ++ct){
        float z = acc[rt][ct][ri] + bia[ct];
        s += z; q += z*z;
      }
#pragma unroll
      for (int m = 1; m < 16; m <<= 1){ s += __shfl_xor(s, m); q += __shfl_xor(q, m); }
      if (il == 0){
        int row = wr*64 + rt*16 + lg*4 + ri;
        sh.red[(row*2 + wc)*2 + 0] = s;
        sh.red[(row*2 + wc)*2 + 1] = q;
      }
    }
  __syncthreads();
  if (tid < 128){
    float s = sh.red[(tid*2+0)*2+0] + sh.red[(tid*2+1)*2+0];
    float q = sh.red[(tid*2+0)*2+1] + sh.red[(tid*2+1)*2+1];
    float mean = s * (1.f/128.f);
    float var  = q * (1.f/128.f) - mean*mean;
    sh.stats[tid*2+0] = mean;
    sh.stats[tid*2+1] = rsqrtf(var + 1e-5f);
  }
  __syncthreads();
}

// =======================  kernels  =======================

// CSR-binned segment mean: block = (b, group of 8 clusters). Scan idx once from LDS,
// bin row indices; then each HALF-WAVE (32 lanes, float4 = full 512B row) owns one cluster.
__global__ __launch_bounds__(TPB) void k_pool(const float* __restrict__ fine,
                                              const int* __restrict__ idx,
                                              unsigned short* __restrict__ pooled){
  int b = blockIdx.x >> 6, g = blockIdx.x & 63;
  int c0 = g * 8;
  __shared__ int sidx[4096];
  __shared__ int rows[512];
  __shared__ int cnt[8], off[9], woff[8];
  int tid = threadIdx.x;
  const int* idx_b = idx + b*4096;
  for (int i = tid; i < 4096; i += TPB) sidx[i] = idx_b[i];
  if (tid < 8) cnt[tid] = 0;
  __syncthreads();
  for (int i = tid; i < 4096; i += TPB){
    unsigned d = (unsigned)(sidx[i] - c0);
    if (d < 8u) atomicAdd(&cnt[d], 1);
  }
  __syncthreads();
  if (tid == 0){
    int s = 0;
#pragma unroll
    for (int j = 0; j < 8; ++j){ off[j] = s; s += cnt[j]; }
    off[8] = s;
  }
  __syncthreads();
  if (tid < 8) woff[tid] = off[tid];
  __syncthreads();
  for (int i = tid; i < 4096; i += TPB){
    unsigned d = (unsigned)(sidx[i] - c0);
    if (d < 8u){ int p = atomicAdd(&woff[d], 1); if (p < 512) rows[p] = i; }
  }
  __syncthreads();
  // 8 half-waves, one cluster each; 32 lanes x float4 covers the 128 cols
  int hw = tid >> 5, l32 = tid & 31;
  const float* fb = fine + (size_t)b*4096*128;
  int o0 = off[hw], o1 = off[hw+1];
  float4 s = {0.f, 0.f, 0.f, 0.f};
  for (int m = o0; m < o1; ++m){
    float4 v = *((const float4*)(fb + (size_t)rows[m]*128) + l32);
    s.x += v.x; s.y += v.y; s.z += v.z; s.w += v.w;
  }
  float inv = 1.f / fmaxf((float)(o1 - o0), 1.f);
  unsigned short* po = pooled + ((size_t)(b*512 + c0 + hw))*128 + l32*4;
  po[0] = f2bf(s.x*inv); po[1] = f2bf(s.y*inv);
  po[2] = f2bf(s.z*inv); po[3] = f2bf(s.w*inv);
}

// per-batch sum over N of global_features (scaled at use time)
__global__ __launch_bounds__(TPB) void k_gmean(const float* __restrict__ glob,
                                               float* __restrict__ gmean){
  int b = blockIdx.x >> 5, s = blockIdx.x & 31;
  int tid = threadIdx.x;
  int h = tid & 127, half = tid >> 7;
  __shared__ float part[128];
  const float* gb = glob + ((size_t)b*4096 + s*128)*128;
  float acc = 0.f;
  for (int r = half; r < 128; r += 2) acc += gb[(size_t)r*128 + h];
  if (half) part[h] = acc;
  __syncthreads();
  if (!half) atomicAdd(&gmean[b*128 + h], acc + part[h]);
}

// W [K][128] fp32 -> Wt [128][K] bf16
__global__ void k_prep(const float* __restrict__ Wp, const float* __restrict__ Wu,
                       const float* __restrict__ Wg, const float* __restrict__ Wgl,
                       unsigned short* __restrict__ WtP, unsigned short* __restrict__ WtU,
                       unsigned short* __restrict__ WtG, unsigned short* __restrict__ WtGl){
  int i = blockIdx.x * blockDim.x + threadIdx.x;
  if (i < 16384){
    int n = i >> 7, k = i & 127;
    WtP[n*128 + k] = f2bf(Wp[k*128 + n]);
    WtU[n*128 + k] = f2bf(Wu[k*128 + n]);
  }
  if (i < 32768){
    int n = i >> 8, k = i & 255;
    WtG [n*256 + k] = f2bf(Wg [k*128 + n]);
    WtGl[n*256 + k] = f2bf(Wgl[k*128 + n]);
  }
}

// Fused per-path pipeline over a 128-row tile:
//   u1 = relu(LN(x1@W1 + b1)*g1 + be1)            (x1: gather(coarse,idx) | pooled)
//   gate = sigmoid([a,u1]@Wg + bg); u2 = gate*a + (1-gate)*u1
//   wg = relu(LN([u2,gl]@Wgl + bgl)*ggl + begl); out = u2 + 0.1*wg
template<int PATH>   // 0 = fine path, 1 = coarse path
__global__ __launch_bounds__(TPB) void k_mega(
    const float* __restrict__ a_src,         // fine | coarse  fp32 [rows][128]
    const float* __restrict__ gath_src,      // coarse input (PATH0) | unused
    const unsigned short* __restrict__ x1b,  // unused | pooled bf16
    const int* __restrict__ idx,             // PATH0 | unused
    const float* __restrict__ gsrc,          // glob rows (PATH0) | gmean (PATH1)
    float gscale,
    const unsigned short* __restrict__ Wt1, const float* __restrict__ b1,
    const float* __restrict__ g1, const float* __restrict__ be1,
    const unsigned short* __restrict__ WtG, const float* __restrict__ bG,
    const unsigned short* __restrict__ WtGl, const float* __restrict__ bGl,
    const float* __restrict__ gGl, const float* __restrict__ beGl,
    float* __restrict__ out)
{
  __shared__ MegaShared sh;
  int tid = threadIdx.x;
  int row0 = blockIdx.x * 128;
  int b  = (PATH == 0) ? (row0 >> 12) : (row0 >> 9);
  int r0 = (PATH == 0) ? (row0 & 4095) : 0;
  int wave = tid >> 6, lane = tid & 63;
  int wr = wave >> 1, wc = wave & 1, il = lane & 15, lg = lane >> 4;

  // ---------- GEMM1: K=128 ----------
  f32x4 acc[4][4] = {};
#pragma unroll
  for (int c = 0; c < 2; ++c){
    int k0 = c*64;
    stage_w(Wt1, 128, k0, sh.wlds, tid);
    if (PATH == 0) stage_x_gather(gath_src + (size_t)b*512*128, idx + b*4096, r0, k0, sh.xlds, tid);
    else           stage_x_bf16(x1b + (size_t)row0*128 + k0, sh.xlds, tid);
    __syncthreads();
    gemm_chunk(sh.xlds, sh.wlds, acc, wr, wc, il, lg);
    __syncthreads();
  }
  float bia[4], gmv[4], btv[4];
#pragma unroll
  for (int ct = 0; ct < 4; ++ct){
    int col = wc*64 + ct*16 + il;
    bia[ct] = b1[col]; gmv[ct] = g1[col]; btv[ct] = be1[col];
  }
  ln_stats(sh, acc, bia, wr, wc, il, lg, tid);
#pragma unroll
  for (int rt = 0; rt < 4; ++rt)
#pragma unroll
    for (int ri = 0; ri < 4; ++ri){
      int row = wr*64 + rt*16 + lg*4 + ri;
      float mean = sh.stats[row*2+0], rstd = sh.stats[row*2+1];
#pragma unroll
      for (int ct = 0; ct < 4; ++ct){
        float z = acc[rt][ct][ri] + bia[ct];
        float y = fmaxf((z - mean)*rstd*gmv[ct] + btv[ct], 0.f);
        sh.ubuf[wc][row*CHP + ct*16 + il] = f2bf(y);
      }
    }
  // (u1 writes become visible at the next barrier; first read is 2+ barriers later)

  // ---------- GEMM2: gate, K=256 ----------
#pragma unroll
  for (int rt = 0; rt < 4; ++rt)
#pragma unroll
    for (int ct = 0; ct < 4; ++ct) acc[rt][ct] = (f32x4){0.f,0.f,0.f,0.f};
#pragma unroll
  for (int c = 0; c < 4; ++c){
    int k0 = c*64;
    stage_w(WtG, 256, k0, sh.wlds, tid);
    if (c < 2) stage_x_f32(a_src + (size_t)row0*128 + k0, sh.xlds, tid);
    __syncthreads();
    gemm_chunk(c < 2 ? sh.xlds : sh.ubuf[c-2], sh.wlds, acc, wr, wc, il, lg);
    __syncthreads();
  }
  float u2r[4][4][4];
#pragma unroll
  for (int ct = 0; ct < 4; ++ct) bia[ct] = bG[wc*64 + ct*16 + il];
#pragma unroll
  for (int rt = 0; rt < 4; ++rt)
#pragma unroll
    for (int ri = 0; ri < 4; ++ri){
      int row = wr*64 + rt*16 + lg*4 + ri;
      size_t gro = (size_t)(row0 + row)*128;
#pragma unroll
      for (int ct = 0; ct < 4; ++ct){
        int col = wc*64 + ct*16 + il;
        float z = acc[rt][ct][ri] + bia[ct];
        float gt = 1.f / (1.f + __expf(-z));
        float f  = a_src[gro + col];
        int ua = row*CHP + ct*16 + il;
        float u1 = bf2f(sh.ubuf[wc][ua]);
        float u2 = gt*f + (1.f - gt)*u1;
        u2r[rt][ct][ri] = u2;
        sh.ubuf[wc][ua] = f2bf(u2);   // own addr: read-then-write by same thread only
      }
    }

  // ---------- GEMM3: glob, K=256 ----------
#pragma unroll
  for (int rt = 0; rt < 4; ++rt)
#pragma unroll
    for (int ct = 0; ct < 4; ++ct) acc[rt][ct] = (f32x4){0.f,0.f,0.f,0.f};
#pragma unroll
  for (int c = 0; c < 4; ++c){
    int k0 = c*64;
    stage_w(WtGl, 256, k0, sh.wlds, tid);
    if (c >= 2){
      if (PATH == 0) stage_x_f32(gsrc + (size_t)row0*128 + (k0-128), sh.xlds, tid);
      else           stage_x_bcast(gsrc + b*128, gscale, k0-128, sh.xlds, tid);
    }
    __syncthreads();
    gemm_chunk(c < 2 ? sh.ubuf[c] : sh.xlds, sh.wlds, acc, wr, wc, il, lg);
    __syncthreads();
  }
#pragma unroll
  for (int ct = 0; ct < 4; ++ct){
    int col = wc*64 + ct*16 + il;
    bia[ct] = bGl[col]; gmv[ct] = gGl[col]; btv[ct] = beGl[col];
  }
  ln_stats(sh, acc, bia, wr, wc, il, lg, tid);
#pragma unroll
  for (int rt = 0; rt < 4; ++rt)
#pragma unroll
    for (int ri = 0; ri < 4; ++ri){
      int row = wr*64 + rt*16 + lg*4 + ri;
      float mean = sh.stats[row*2+0], rstd = sh.stats[row*2+1];
      size_t gro = (size_t)(row0 + row)*128;
#pragma unroll
      for (int ct = 0; ct < 4; ++ct){
        int col = wc*64 + ct*16 + il;
        float z = acc[rt][ct][ri] + bia[ct];
        float y = fmaxf((z - mean)*rstd*gmv[ct] + btv[ct], 0.f);
        out[gro + col] = u2r[rt][ct][ri] + 0.1f*y;
      }
    }
}

extern "C" void kernel_launch(void* const* d_in, const int* in_sizes, int n_in,
                              void* d_out, int out_size, void* d_ws, size_t ws_size,
                              hipStream_t stream){
  const float* fine    = (const float*)d_in[0];
  const float* coarse  = (const float*)d_in[1];
  const float* glob    = (const float*)d_in[2];
  const int*   idx     = (const int*)  d_in[3];
  const float* W_pool  = (const float*)d_in[4];
  const float* b_pool  = (const float*)d_in[5];
  const float* g_pool  = (const float*)d_in[6];
  const float* be_pool = (const float*)d_in[7];
  const float* W_unpool  = (const float*)d_in[8];
  const float* b_unpool  = (const float*)d_in[9];
  const float* g_unpool  = (const float*)d_in[10];
  const float* be_unpool = (const float*)d_in[11];
  const float* W_gate = (const float*)d_in[12];
  const float* b_gate = (const float*)d_in[13];
  const float* W_glob = (const float*)d_in[14];
  const float* b_glob = (const float*)d_in[15];
  const float* g_glob = (const float*)d_in[16];
  const float* be_glob= (const float*)d_in[17];

  const int B = 32, N = 4096, C = 512;
  float* out_fine   = (float*)d_out;
  float* out_coarse = out_fine + (size_t)B*N*128;

  char* w = (char*)d_ws;
  unsigned short* WtP  = (unsigned short*)w; w += 128*128*2;
  unsigned short* WtU  = (unsigned short*)w; w += 128*128*2;
  unsigned short* WtG  = (unsigned short*)w; w += 128*256*2;
  unsigned short* WtGl = (unsigned short*)w; w += 128*256*2;
  float* gmean = (float*)w;                  w += B*128*4;
  unsigned short* pooled = (unsigned short*)w; w += (size_t)B*C*128*2;

  hipMemsetAsync(gmean, 0, B*128*4, stream);
  k_prep<<<128, TPB, 0, stream>>>(W_pool, W_unpool, W_gate, W_glob, WtP, WtU, WtG, WtGl);
  k_pool<<<B*64, TPB, 0, stream>>>(fine, idx, pooled);
  k_gmean<<<B*32, TPB, 0, stream>>>(glob, gmean);

  // fine path: unpool(gather) -> gate -> glob
  k_mega<0><<<(B*N)/128, TPB, 0, stream>>>(fine, coarse, nullptr, idx, glob, 1.0f,
                                           WtU, b_unpool, g_unpool, be_unpool,
                                           WtG, b_gate, WtGl, b_glob, g_glob, be_glob,
                                           out_fine);
  // coarse path: pool-block -> gate -> glob
  k_mega<1><<<(B*C)/128, TPB, 0, stream>>>(coarse, nullptr, pooled, nullptr, gmean, 1.f/4096.f,
                                           WtP, b_pool, g_pool, be_pool,
                                           WtG, b_gate, WtGl, b_glob, g_glob, be_glob,
                                           out_coarse);
}

// Round 4
// 149.263 us; speedup vs baseline: 2.2443x; 1.7514x over previous
//
#include <hip/hip_runtime.h>

typedef __bf16 bf16;
typedef bf16 bf16x8 __attribute__((ext_vector_type(8)));
typedef float f32x4 __attribute__((ext_vector_type(4)));

#define TPB 256
#define CHP 72   // padded LDS row stride (ushorts) for a 64-wide K chunk: 144B = 9*16B

__device__ inline unsigned short f2bf(float f){
  union{ bf16 h; unsigned short u; } v; v.h = (bf16)f; return v.u;
}
__device__ inline float bf2f(unsigned short u){
  union{ unsigned short u; bf16 h; } v; v.u = u; return (float)v.h;
}
__device__ inline unsigned int pk2(float a, float b){
  return (unsigned int)f2bf(a) | ((unsigned int)f2bf(b) << 16);
}

struct __align__(16) MegaShared {
  unsigned short xbuf[2][64*CHP];   // 2 x 9216 B (staging double buffer)
  unsigned short ubuf[2][64*CHP];   // 18432 B (u intermediate, 2 x 64-K chunks)
  float red[64*2*2];                // 1024 B
  float stats[64*2];                // 512 B
};                                  // ~38.4 KB -> LDS allows 4 blocks/CU; VGPR caps at 3

// ---- register staging (64 rows x 64-k chunk), split issue/write ----
struct StReg { uint2 v[4]; };

__device__ inline StReg sload_f32(const float* __restrict__ src, int tid){
  StReg g;
#pragma unroll
  for (int i = 0; i < 4; ++i){
    int p = tid + i*TPB; int r = p >> 4, q = p & 15;
    float4 v = *(const float4*)(src + (size_t)r*128 + q*4);
    g.v[i].x = pk2(v.x, v.y); g.v[i].y = pk2(v.z, v.w);
  }
  return g;
}
__device__ inline StReg sload_bf16(const unsigned short* __restrict__ src, int tid){
  StReg g;
#pragma unroll
  for (int i = 0; i < 4; ++i){
    int p = tid + i*TPB; int r = p >> 4, q = p & 15;
    g.v[i] = *(const uint2*)(src + (size_t)r*128 + q*4);
  }
  return g;
}
__device__ inline StReg sload_gather(const float* __restrict__ coarse_b, const int* __restrict__ ib,
                                     int k0, int tid){
  StReg g;
#pragma unroll
  for (int i = 0; i < 4; ++i){
    int p = tid + i*TPB; int r = p >> 4, q = p & 15;
    int ci = ib[r];
    float4 v = {0.f, 0.f, 0.f, 0.f};
    if ((unsigned)ci < 512u) v = *(const float4*)(coarse_b + (size_t)ci*128 + k0 + q*4);
    g.v[i].x = pk2(v.x, v.y); g.v[i].y = pk2(v.z, v.w);
  }
  return g;
}
__device__ inline StReg sload_bcast(const float* __restrict__ gm, float scale, int k0, int tid){
  StReg g;
#pragma unroll
  for (int i = 0; i < 4; ++i){
    int p = tid + i*TPB; int q = p & 15;
    float4 v = *(const float4*)(gm + k0 + q*4);
    g.v[i].x = pk2(v.x*scale, v.y*scale); g.v[i].y = pk2(v.z*scale, v.w*scale);
  }
  return g;
}
__device__ inline void swrite(unsigned short* buf, const StReg& g, int tid){
#pragma unroll
  for (int i = 0; i < 4; ++i){
    int p = tid + i*TPB; int r = p >> 4, q = p & 15;
    *(uint2*)(buf + r*CHP + q*4) = g.v[i];
  }
}

// ---- B fragments: direct, coalesced loads from fragment-ordered weights ----
__device__ inline void bload(const unsigned short* __restrict__ Wf, int c, int wc, int lane,
                             bf16x8 b[2][4]){
#pragma unroll
  for (int kk = 0; kk < 2; ++kk)
#pragma unroll
    for (int t = 0; t < 4; ++t)
      b[kk][t] = *(const bf16x8*)(Wf + (size_t)((((c*8 + wc*4 + t)*2) + kk)*64 + lane)*8);
}

// ---- one 64-K chunk of MFMA for a 32x64 wave tile ----
__device__ inline void mfma_chunk(const unsigned short* asrc, const bf16x8 b[2][4],
                                  f32x4 acc[2][4], int wr, int il, int lg){
#pragma unroll
  for (int kk = 0; kk < 2; ++kk){
    bf16x8 a[2];
#pragma unroll
    for (int t = 0; t < 2; ++t)
      a[t] = *(const bf16x8*)(asrc + (wr*32 + t*16 + il)*CHP + kk*32 + lg*8);
#pragma unroll
    for (int rt = 0; rt < 2; ++rt)
#pragma unroll
      for (int ct = 0; ct < 4; ++ct)
        acc[rt][ct] = __builtin_amdgcn_mfma_f32_16x16x32_bf16(a[rt], b[kk][ct], acc[rt][ct], 0, 0, 0);
  }
}

// ---- LN stats (64 rows, 2 col-waves) ----
__device__ inline void ln_stats(MegaShared& sh, f32x4 acc[2][4], const float bia[4],
                                int wr, int wc, int il, int lg, int tid){
#pragma unroll
  for (int rt = 0; rt < 2; ++rt)
#pragma unroll
    for (int ri = 0; ri < 4; ++ri){
      float s = 0.f, q = 0.f;
#pragma unroll
      for (int ct = 0; ct < 4; ++ct){
        float z = acc[rt][ct][ri] + bia[ct];
        s += z; q += z*z;
      }
#pragma unroll
      for (int m = 1; m < 16; m <<= 1){ s += __shfl_xor(s, m); q += __shfl_xor(q, m); }
      if (il == 0){
        int row = wr*32 + rt*16 + lg*4 + ri;
        sh.red[(row*2 + wc)*2 + 0] = s;
        sh.red[(row*2 + wc)*2 + 1] = q;
      }
    }
  __syncthreads();
  if (tid < 64){
    float s = sh.red[(tid*2+0)*2+0] + sh.red[(tid*2+1)*2+0];
    float q = sh.red[(tid*2+0)*2+1] + sh.red[(tid*2+1)*2+1];
    float mean = s * (1.f/128.f);
    float var  = q * (1.f/128.f) - mean*mean;
    sh.stats[tid*2+0] = mean;
    sh.stats[tid*2+1] = rsqrtf(var + 1e-5f);
  }
  __syncthreads();
}

// =======================  kernels  =======================

// CSR-binned segment mean (unchanged from round 3 — verified)
__global__ __launch_bounds__(TPB) void k_pool(const float* __restrict__ fine,
                                              const int* __restrict__ idx,
                                              unsigned short* __restrict__ pooled){
  int b = blockIdx.x >> 6, g = blockIdx.x & 63;
  int c0 = g * 8;
  __shared__ int sidx[4096];
  __shared__ int rows[512];
  __shared__ int cnt[8], off[9], woff[8];
  int tid = threadIdx.x;
  const int* idx_b = idx + b*4096;
  for (int i = tid; i < 4096; i += TPB) sidx[i] = idx_b[i];
  if (tid < 8) cnt[tid] = 0;
  __syncthreads();
  for (int i = tid; i < 4096; i += TPB){
    unsigned d = (unsigned)(sidx[i] - c0);
    if (d < 8u) atomicAdd(&cnt[d], 1);
  }
  __syncthreads();
  if (tid == 0){
    int s = 0;
#pragma unroll
    for (int j = 0; j < 8; ++j){ off[j] = s; s += cnt[j]; }
    off[8] = s;
  }
  __syncthreads();
  if (tid < 8) woff[tid] = off[tid];
  __syncthreads();
  for (int i = tid; i < 4096; i += TPB){
    unsigned d = (unsigned)(sidx[i] - c0);
    if (d < 8u){ int p = atomicAdd(&woff[d], 1); if (p < 512) rows[p] = i; }
  }
  __syncthreads();
  int hw = tid >> 5, l32 = tid & 31;
  const float* fb = fine + (size_t)b*4096*128;
  int o0 = off[hw], o1 = off[hw+1];
  float4 s = {0.f, 0.f, 0.f, 0.f};
  for (int m = o0; m < o1; ++m){
    float4 v = *((const float4*)(fb + (size_t)rows[m]*128) + l32);
    s.x += v.x; s.y += v.y; s.z += v.z; s.w += v.w;
  }
  float inv = 1.f / fmaxf((float)(o1 - o0), 1.f);
  unsigned short* po = pooled + ((size_t)(b*512 + c0 + hw))*128 + l32*4;
  po[0] = f2bf(s.x*inv); po[1] = f2bf(s.y*inv);
  po[2] = f2bf(s.z*inv); po[3] = f2bf(s.w*inv);
}

__global__ __launch_bounds__(TPB) void k_gmean(const float* __restrict__ glob,
                                               float* __restrict__ gmean){
  int b = blockIdx.x >> 5, s = blockIdx.x & 31;
  int tid = threadIdx.x;
  int h = tid & 127, half = tid >> 7;
  __shared__ float part[128];
  const float* gb = glob + ((size_t)b*4096 + s*128)*128;
  float acc = 0.f;
  for (int r = half; r < 128; r += 2) acc += gb[(size_t)r*128 + h];
  if (half) part[h] = acc;
  __syncthreads();
  if (!half) atomicAdd(&gmean[b*128 + h], acc + part[h]);
}

// W [K][128] fp32 -> B-fragment-ordered bf16:
// elem e: j=e&7, lane=(e>>3)&63, frag=e>>9; kk=frag&1, nblk=(frag>>1)&7, c=frag>>4;
// col = nblk*16 + (lane&15); k = c*64 + kk*32 + (lane>>4)*8 + j; value = W[k*128+col]
__global__ __launch_bounds__(TPB) void k_prep(const float* __restrict__ Wp, const float* __restrict__ Wu,
                       const float* __restrict__ Wg, const float* __restrict__ Wgl,
                       unsigned short* __restrict__ WfP, unsigned short* __restrict__ WfU,
                       unsigned short* __restrict__ WfG, unsigned short* __restrict__ WfGl){
  int e = blockIdx.x * TPB + threadIdx.x;      // 0..32767
  int j = e & 7, lane = (e >> 3) & 63, frag = e >> 9;
  int kk = frag & 1, nblk = (frag >> 1) & 7, c = frag >> 4;
  int il = lane & 15, lg = lane >> 4;
  int col = nblk*16 + il;
  int k = c*64 + kk*32 + lg*8 + j;
  if (e < 16384){
    WfP[e] = f2bf(Wp[k*128 + col]);
    WfU[e] = f2bf(Wu[k*128 + col]);
  }
  WfG[e]  = f2bf(Wg[k*128 + col]);
  WfGl[e] = f2bf(Wgl[k*128 + col]);
}

// Fused per-path pipeline over a 64-row tile (2x2 waves of 32x64):
//   u1 = relu(LN(x1@W1 + b1)*g1 + be1)            (x1: gather(coarse,idx) | pooled)
//   gate = sigmoid([a,u1]@Wg + bg); u2 = gate*a + (1-gate)*u1
//   wg = relu(LN([u2,gl]@Wgl + bgl)*ggl + begl); out = u2 + 0.1*wg
template<int PATH>   // 0 = fine path, 1 = coarse path
__global__ __launch_bounds__(TPB, 3) void k_mega(
    const float* __restrict__ a_src,
    const float* __restrict__ gath_src,
    const unsigned short* __restrict__ x1b,
    const int* __restrict__ idx,
    const float* __restrict__ gsrc,
    float gscale,
    const unsigned short* __restrict__ Wf1, const float* __restrict__ b1,
    const float* __restrict__ g1, const float* __restrict__ be1,
    const unsigned short* __restrict__ WfG, const float* __restrict__ bG,
    const unsigned short* __restrict__ WfGl, const float* __restrict__ bGl,
    const float* __restrict__ gGl, const float* __restrict__ beGl,
    float* __restrict__ out)
{
  __shared__ MegaShared sh;
  int tid = threadIdx.x;
  int row0 = blockIdx.x * 64;
  int b  = (PATH == 0) ? (row0 >> 12) : (row0 >> 9);
  int r0 = (PATH == 0) ? (row0 & 4095) : 0;
  int wave = tid >> 6, lane = tid & 63;
  int wr = wave >> 1, wc = wave & 1, il = lane & 15, lg = lane >> 4;

  const float* cb = (PATH == 0) ? gath_src + (size_t)b*512*128 : nullptr;
  const int*   ib = (PATH == 0) ? idx + b*4096 + r0 : nullptr;
  const float* arow = a_src + (size_t)row0*128;

  f32x4 acc[2][4] = {};
  StReg g;
  bf16x8 bfr[2][4];

  // ===== GEMM1 (K=128) =====
  if (PATH == 0) g = sload_gather(cb, ib, 0, tid);
  else           g = sload_bf16(x1b + (size_t)row0*128, tid);
  swrite(sh.xbuf[0], g, tid);
  bload(Wf1, 0, wc, lane, bfr);
  if (PATH == 0) g = sload_gather(cb, ib, 64, tid);
  else           g = sload_bf16(x1b + (size_t)row0*128 + 64, tid);
  __syncthreads();                              // xbuf[0] visible
  mfma_chunk(sh.xbuf[0], bfr, acc, wr, il, lg);
  swrite(sh.xbuf[1], g, tid);
  bload(Wf1, 1, wc, lane, bfr);
  __syncthreads();                              // xbuf[1] visible
  mfma_chunk(sh.xbuf[1], bfr, acc, wr, il, lg);

  g = sload_f32(arow, tid);                     // issue GEMM2 chunk0 early

  float bia[4], gmv[4], btv[4];
#pragma unroll
  for (int ct = 0; ct < 4; ++ct){
    int col = wc*64 + ct*16 + il;
    bia[ct] = b1[col]; gmv[ct] = g1[col]; btv[ct] = be1[col];
  }
  ln_stats(sh, acc, bia, wr, wc, il, lg, tid);
#pragma unroll
  for (int rt = 0; rt < 2; ++rt)
#pragma unroll
    for (int ri = 0; ri < 4; ++ri){
      int row = wr*32 + rt*16 + lg*4 + ri;
      float mean = sh.stats[row*2], rstd = sh.stats[row*2+1];
#pragma unroll
      for (int ct = 0; ct < 4; ++ct){
        float z = acc[rt][ct][ri] + bia[ct];
        float y = fmaxf((z - mean)*rstd*gmv[ct] + btv[ct], 0.f);
        sh.ubuf[wc][row*CHP + ct*16 + il] = f2bf(y);
      }
    }
  // u1 writes made visible by GEMM2's first barrier (first ubuf read is chunk 2)

  // ===== GEMM2 (gate, K=256: [a | u1]) =====
#pragma unroll
  for (int rt = 0; rt < 2; ++rt)
#pragma unroll
    for (int ct = 0; ct < 4; ++ct) acc[rt][ct] = (f32x4){0.f,0.f,0.f,0.f};
  swrite(sh.xbuf[0], g, tid);                   // xbuf free: all waves past ln_stats barriers
  bload(WfG, 0, wc, lane, bfr);
  g = sload_f32(arow + 64, tid);
  __syncthreads();                              // xbuf[0] + u1 visible
  mfma_chunk(sh.xbuf[0], bfr, acc, wr, il, lg);
  swrite(sh.xbuf[1], g, tid);
  bload(WfG, 1, wc, lane, bfr);
  __syncthreads();
  mfma_chunk(sh.xbuf[1], bfr, acc, wr, il, lg);
  bload(WfG, 2, wc, lane, bfr);
  mfma_chunk(sh.ubuf[0], bfr, acc, wr, il, lg); // no barrier needed (u1 visible since c0)
  bload(WfG, 3, wc, lane, bfr);
  mfma_chunk(sh.ubuf[1], bfr, acc, wr, il, lg);

  if (PATH == 0) g = sload_f32(gsrc + (size_t)row0*128, tid);     // issue glob chunk0 early
  else           g = sload_bcast(gsrc + b*128, gscale, 0, tid);
  __syncthreads();                              // all ubuf reads done before u2 overwrite

  float u2r[2][4][4];
#pragma unroll
  for (int ct = 0; ct < 4; ++ct) bia[ct] = bG[wc*64 + ct*16 + il];
#pragma unroll
  for (int rt = 0; rt < 2; ++rt)
#pragma unroll
    for (int ri = 0; ri < 4; ++ri){
      int row = wr*32 + rt*16 + lg*4 + ri;
      size_t gro = (size_t)(row0 + row)*128;
#pragma unroll
      for (int ct = 0; ct < 4; ++ct){
        int col = wc*64 + ct*16 + il;
        float z = acc[rt][ct][ri] + bia[ct];
        float gt = 1.f / (1.f + __expf(-z));
        float f  = a_src[gro + col];
        int ua = row*CHP + ct*16 + il;
        float u1 = bf2f(sh.ubuf[wc][ua]);
        float u2 = gt*f + (1.f - gt)*u1;
        u2r[rt][ct][ri] = u2;
        sh.ubuf[wc][ua] = f2bf(u2);             // own addr only
      }
    }
  swrite(sh.xbuf[0], g, tid);                   // xbuf[0] free (GEMM2 c0 done by barrier above)
  if (PATH == 0) g = sload_f32(gsrc + (size_t)row0*128 + 64, tid);
  else           g = sload_bcast(gsrc + b*128, gscale, 64, tid);
  __syncthreads();                              // u2 + xbuf[0] visible

  // ===== GEMM3 (glob, K=256: [u2 | gl]) =====
#pragma unroll
  for (int rt = 0; rt < 2; ++rt)
#pragma unroll
    for (int ct = 0; ct < 4; ++ct) acc[rt][ct] = (f32x4){0.f,0.f,0.f,0.f};
  bload(WfGl, 0, wc, lane, bfr);
  mfma_chunk(sh.ubuf[0], bfr, acc, wr, il, lg);
  swrite(sh.xbuf[1], g, tid);
  bload(WfGl, 1, wc, lane, bfr);
  mfma_chunk(sh.ubuf[1], bfr, acc, wr, il, lg);
  bload(WfGl, 2, wc, lane, bfr);
  __syncthreads();                              // xbuf[1] visible (written before this barrier)
  mfma_chunk(sh.xbuf[0], bfr, acc, wr, il, lg);
  bload(WfGl, 3, wc, lane, bfr);
  mfma_chunk(sh.xbuf[1], bfr, acc, wr, il, lg);

#pragma unroll
  for (int ct = 0; ct < 4; ++ct){
    int col = wc*64 + ct*16 + il;
    bia[ct] = bGl[col]; gmv[ct] = gGl[col]; btv[ct] = beGl[col];
  }
  ln_stats(sh, acc, bia, wr, wc, il, lg, tid);
#pragma unroll
  for (int rt = 0; rt < 2; ++rt)
#pragma unroll
    for (int ri = 0; ri < 4; ++ri){
      int row = wr*32 + rt*16 + lg*4 + ri;
      float mean = sh.stats[row*2], rstd = sh.stats[row*2+1];
      size_t gro = (size_t)(row0 + row)*128;
#pragma unroll
      for (int ct = 0; ct < 4; ++ct){
        int col = wc*64 + ct*16 + il;
        float z = acc[rt][ct][ri] + bia[ct];
        float y = fmaxf((z - mean)*rstd*gmv[ct] + btv[ct], 0.f);
        out[gro + col] = u2r[rt][ct][ri] + 0.1f*y;
      }
    }
}

extern "C" void kernel_launch(void* const* d_in, const int* in_sizes, int n_in,
                              void* d_out, int out_size, void* d_ws, size_t ws_size,
                              hipStream_t stream){
  const float* fine    = (const float*)d_in[0];
  const float* coarse  = (const float*)d_in[1];
  const float* glob    = (const float*)d_in[2];
  const int*   idx     = (const int*)  d_in[3];
  const float* W_pool  = (const float*)d_in[4];
  const float* b_pool  = (const float*)d_in[5];
  const float* g_pool  = (const float*)d_in[6];
  const float* be_pool = (const float*)d_in[7];
  const float* W_unpool  = (const float*)d_in[8];
  const float* b_unpool  = (const float*)d_in[9];
  const float* g_unpool  = (const float*)d_in[10];
  const float* be_unpool = (const float*)d_in[11];
  const float* W_gate = (const float*)d_in[12];
  const float* b_gate = (const float*)d_in[13];
  const float* W_glob = (const float*)d_in[14];
  const float* b_glob = (const float*)d_in[15];
  const float* g_glob = (const float*)d_in[16];
  const float* be_glob= (const float*)d_in[17];

  const int B = 32, N = 4096, C = 512;
  float* out_fine   = (float*)d_out;
  float* out_coarse = out_fine + (size_t)B*N*128;

  char* w = (char*)d_ws;
  unsigned short* WfP  = (unsigned short*)w; w += 16384*2;
  unsigned short* WfU  = (unsigned short*)w; w += 16384*2;
  unsigned short* WfG  = (unsigned short*)w; w += 32768*2;
  unsigned short* WfGl = (unsigned short*)w; w += 32768*2;
  float* gmean = (float*)w;                  w += B*128*4;
  unsigned short* pooled = (unsigned short*)w; w += (size_t)B*C*128*2;

  hipMemsetAsync(gmean, 0, B*128*4, stream);
  k_prep<<<128, TPB, 0, stream>>>(W_pool, W_unpool, W_gate, W_glob, WfP, WfU, WfG, WfGl);
  k_pool<<<B*64, TPB, 0, stream>>>(fine, idx, pooled);
  k_gmean<<<B*32, TPB, 0, stream>>>(glob, gmean);

  // fine path: unpool(gather) -> gate -> glob
  k_mega<0><<<(B*N)/64, TPB, 0, stream>>>(fine, coarse, nullptr, idx, glob, 1.0f,
                                          WfU, b_unpool, g_unpool, be_unpool,
                                          WfG, b_gate, WfGl, b_glob, g_glob, be_glob,
                                          out_fine);
  // coarse path: pool-block -> gate -> glob
  k_mega<1><<<(B*C)/64, TPB, 0, stream>>>(coarse, nullptr, pooled, nullptr, gmean, 1.f/4096.f,
                                          WfP, b_pool, g_pool, be_pool,
                                          WfG, b_gate, WfGl, b_glob, g_glob, be_glob,
                                          out_coarse);
}